// Round 6
// baseline (307.192 us; speedup 1.0000x reference)
//
#include <hip/hip_runtime.h>

// RoI2Det fused single-kernel: producers (500 blocks) do softmax->threshold->
// key append + global score histogram; consumers (4 blocks, one per image)
// spin on a device-scope counter, then: hier. threshold select -> ballot
// compaction -> rank-sort -> IoU bit-matrix -> DPP-min greedy bit-scan -> top-100.
// B=4, N=2000, C=80 (81 logits w/ background).
//
// Exactness: greedy NMS output depends only on the sorted prefix down to the
// 100th survivor. Mode A sorts the exact top-S (S in [TARGET,CAPA]) selected by
// a fine score histogram (bucket = key>>46, monotone in score). If <100 keeps
// occur inside the prefix, mode B rebuilds the exact top-2000 (= reference
// candidate set) and redoes NMS — exact by construction.
//
// Producer->consumer coherence (single kernel, cross-XCD): keys stored with
// agent-scope atomic stores (write-through to device coherence point), hist/
// counters via device-scope atomicAdd, publication via release fetch_add on
// `done`; consumers acquire-spin then fence. No co-residency requirement:
// producers always exit, so spinning consumers can never starve them.
//
// ws: [0,64) gcnt int[B][SEG]; [64,68) done; [128,128+B*NBPAD*4) ghist;
//     [38016, +B*CAPIMG*8) keys.  memset [0,38016) each launch.
// key = (score_bits<<32) | (0xFFFFFFFF - flat_idx): desc order == lax.top_k order.

typedef unsigned long long u64;
typedef unsigned int u32;

#define B_ 4
#define N_ 2000
#define C_ 80
#define NCLS 81
#define SEG 4
#define SEGCAP 2048
#define CAPIMG 8192     // SEG*SEGCAP
#define KPRE 2000
#define MAXDET 100
#define TARGET 400      // mode-A prefix floor (100th survivor ~ rank 130)
#define NB 2312         // score buckets: (bits>>14) - HBASE
#define NBPAD 2368      // 37*64
#define NG 37
#define HBASE 0xF500
#define KSHIFT 46       // key>>46 == score_bits>>14 (monotone in score)
#define CAPA 512        // matrix-NMS capacity
#define CAPB 2048       // escalated prefix capacity
#define NPROD 500
#define NCONS 4
#define BIGI 0x7fffffff

__device__ __forceinline__ u64 pack_key(float score, unsigned fi) {
  return ((u64)__float_as_uint(score) << 32) | (u64)(0xFFFFFFFFu - fi);
}

// min over lanes 0..7 (lanes 8..63 must hold BIGI); result valid in lane 0.
__device__ __forceinline__ int dpp_min8(int v) {
  int t;
  t = __builtin_amdgcn_update_dpp(BIGI, v, 0x114, 0xF, 0xF, false);  // row_shr:4
  v = min(v, t);
  t = __builtin_amdgcn_update_dpp(BIGI, v, 0x112, 0xF, 0xF, false);  // row_shr:2
  v = min(v, t);
  t = __builtin_amdgcn_update_dpp(BIGI, v, 0x111, 0xF, 0xF, false);  // row_shr:1
  v = min(v, t);
  return v;
}

__device__ __forceinline__ float4 decode_one(
    u64 kk, const float* __restrict__ reg, const float* __restrict__ props,
    int b, float h, float w, float offscale) {
  const float MAXR = 4.135166556742356f;  // |log(16/1000)|
  unsigned fi = 0xFFFFFFFFu - (u32)kk;
  int n = (int)(fi / (unsigned)C_);
  int c = (int)(fi - (unsigned)n * (unsigned)C_);
  float4 p = ((const float4*)props)[b * N_ + n];
  const float* dl = reg + ((size_t)(b * N_ + n)) * (C_ * 4) + c * 4;
  float dx = dl[0] * 0.1f;
  float dy = dl[1] * 0.1f;
  float dw = fminf(fmaxf(dl[2] * 0.2f, -MAXR), MAXR);
  float dh = fminf(fmaxf(dl[3] * 0.2f, -MAXR), MAXR);
  float px = (p.x + p.z) * 0.5f, py = (p.y + p.w) * 0.5f;
  float pw = p.z - p.x, ph = p.w - p.y;
  float gx = px + pw * dx, gy = py + ph * dy;
  float gw = pw * expf(dw), gh = ph * expf(dh);
  float off = (float)c * offscale;  // cross-class IoU exactly 0 after offset
  return make_float4(fminf(fmaxf(gx - gw * 0.5f, 0.0f), w) + off,
                     fminf(fmaxf(gy - gh * 0.5f, 0.0f), h) + off,
                     fminf(fmaxf(gx + gw * 0.5f, 0.0f), w) + off,
                     fminf(fmaxf(gy + gh * 0.5f, 0.0f), h) + off);
}

// Consumer LDS map (60288 B), by liveness (same as R5, minus LDS hist):
//  [0,32768)     rb   u64[512*8]    mode A bit-matrix
//  [0,9248)+[9248,18496) hA/hB      (mode B full scan)
//  [0,32000)     bxB  float4[2000]  (mode B)
//  [18496,34880) U    u64[2048]     unsorted keys (dead after rank-scatter)
//  [34880,51264) SS   u64[2048]     sorted keys (live to end)
//  [51264,59456) bxA  float4[512]   | keepB int[2048] (mode B)
//  [59456,59968) outl int[128]; [59968,60032) misc int[16]; [60032,60288) coarse
// Producer blocks reuse [59456..) for s_wc/s_woff/s_base (different blocks).

__global__ __launch_bounds__(1024) void fused_kernel(
    const float* __restrict__ cls, const float* __restrict__ reg,
    const float* __restrict__ props, const int* __restrict__ hw,
    int* __restrict__ gcnt, u32* __restrict__ done,
    u32* __restrict__ ghist, u64* __restrict__ gkeys,
    float* __restrict__ out) {
  __shared__ u64 lds8[7536];  // 60288 B
  char* bp = (char*)lds8;
  const int tid = threadIdx.x;
  const int wid = tid >> 6, lane = tid & 63;

  if (blockIdx.x >= NCONS) {
    // ================= producer =================
    int* s_wc = (int*)(bp + 59456);
    int* s_woff = (int*)(bp + 59584);
    int* s_base = (int*)(bp + 59712);
    const int u = blockIdx.x - NCONS;
    const int b = u / 125;
    const int blk = u - b * 125;
    const int g = blk & 3;
    const int n = blk * 16 + wid;
    const float* lg = cls + (size_t)(b * N_ + n) * NCLS;
    float x0 = lg[lane];
    float x1 = (lane < NCLS - 64) ? lg[64 + lane] : -3.0e38f;
    float mx = fmaxf(x0, x1);
#pragma unroll
    for (int o = 32; o > 0; o >>= 1) mx = fmaxf(mx, __shfl_xor(mx, o));
    float e0 = expf(x0 - mx);
    float e1 = (lane < NCLS - 64) ? expf(x1 - mx) : 0.0f;
    float sum = e0 + e1;
#pragma unroll
    for (int o = 32; o > 0; o >>= 1) sum += __shfl_xor(sum, o);
    float sc0 = e0 / sum, sc1 = e1 / sum;
    bool p0 = sc0 > 0.05f;
    bool p1 = (lane < C_ - 64) && (sc1 > 0.05f);  // class 80 = background
    u64 m0 = __ballot(p0), m1 = __ballot(p1);
    int c0 = __popcll(m0);
    if (lane == 0) s_wc[wid] = c0 + __popcll(m1);
    __syncthreads();
    if (tid == 0) {
      int acc = 0;
#pragma unroll
      for (int i = 0; i < 16; ++i) { s_woff[i] = acc; acc += s_wc[i]; }
      *s_base = atomicAdd(gcnt + b * SEG + g, acc);
    }
    __syncthreads();
    const int base = *s_base + s_woff[wid];
    const u64 lt = (1ull << lane) - 1;
    u64* gk = gkeys + (size_t)b * CAPIMG + (size_t)g * SEGCAP;
    u32* gh = ghist + b * NBPAD;
    if (p0) {
      int slot = base + __popcll(m0 & lt);
      if (slot < SEGCAP) {
        __hip_atomic_store(&gk[slot], pack_key(sc0, (unsigned)(n * C_ + lane)),
                           __ATOMIC_RELAXED, __HIP_MEMORY_SCOPE_AGENT);
        int bi = (int)(__float_as_uint(sc0) >> 14) - HBASE;
        bi = min(max(bi, 0), NB - 1);
        atomicAdd(&gh[bi], 1u);
      }
    }
    if (p1) {
      int slot = base + c0 + __popcll(m1 & lt);
      if (slot < SEGCAP) {
        __hip_atomic_store(&gk[slot], pack_key(sc1, (unsigned)(n * C_ + 64 + lane)),
                           __ATOMIC_RELAXED, __HIP_MEMORY_SCOPE_AGENT);
        int bi = (int)(__float_as_uint(sc1) >> 14) - HBASE;
        bi = min(max(bi, 0), NB - 1);
        atomicAdd(&gh[bi], 1u);
      }
    }
    __syncthreads();  // drains this block's vmem before publish
    if (tid == 0)
      __hip_atomic_fetch_add(done, 1u, __ATOMIC_RELEASE, __HIP_MEMORY_SCOPE_AGENT);
    return;
  }

  // ================= consumer (one block per image) =================
  u64* rb = (u64*)(bp + 0);
  float4* bxB = (float4*)(bp + 0);
  u64* U = (u64*)(bp + 18496);
  u64* SS = (u64*)(bp + 34880);
  float4* bxA = (float4*)(bp + 51264);
  int* keepB = (int*)(bp + 51264);
  int* outl = (int*)(bp + 59456);
  int* misc = (int*)(bp + 59968);
  int* s_coarse = (int*)(bp + 60032);

  const int b = blockIdx.x;
  const u64* gk = gkeys + (size_t)b * CAPIMG;
  const u32* ghb = ghist + b * NBPAD;
  float h = (float)hw[b * 2 + 0];
  float w = (float)hw[b * 2 + 1];
  float offscale = fmaxf(h, w) + 1.0f;

  // Prefetch props into this XCD's L2 while producers run.
  {
    float acc = 0.0f;
    const float4* pr = (const float4*)props + b * N_;
    for (int t = tid; t < N_; t += 1024) {
      float4 p = pr[t];
      acc += p.x + p.y + p.z + p.w;
    }
    if (acc != acc) ((volatile int*)outl)[126] = 1;  // finite inputs: never taken
  }
  if (tid < 16) misc[tid] = 0;
  if (tid < 64) s_coarse[tid] = 0;

  // Wait for all producers (acquire), then fence.
  if (tid == 0) {
    while (__hip_atomic_load(done, __ATOMIC_ACQUIRE, __HIP_MEMORY_SCOPE_AGENT) <
           (u32)NPROD)
      __builtin_amdgcn_s_sleep(8);
  }
  __syncthreads();
  __threadfence();

  int Mseg[SEG];
  int M = 0;
#pragma unroll
  for (int s = 0; s < SEG; s++) {
    int m = __hip_atomic_load(&gcnt[b * SEG + s], __ATOMIC_RELAXED,
                              __HIP_MEMORY_SCOPE_AGENT);
    m = min(m, SEGCAP);
    Mseg[s] = m;
    M += m;
  }

  // Coarse group sums from the global histogram.
  for (int g2 = wid; g2 < NG; g2 += 16) {
    int v = (int)ghb[(g2 << 6) | lane];
#pragma unroll
    for (int o = 32; o; o >>= 1) v += __shfl_xor(v, o);
    if (lane == 0) s_coarse[g2] = v;
  }
  __syncthreads();

  // T_A selection (wave 0): coarse suffix-scan, then fine scan in one group.
  if (tid < 64) {
    int v = s_coarse[lane];  // lanes >= NG read 0
#pragma unroll
    for (int off = 1; off < 64; off <<= 1) {
      int src = lane + off;
      int o = __shfl(v, src < 64 ? src : 63);
      if (src < 64) v += o;
    }
    u64 pm = __ballot(v >= TARGET);
    int T_A = 0, S_A;
    if (pm) {
      int gs = 63 - __builtin_clzll(pm);
      int beyond = __shfl(v, gs + 1);
      int fv = (int)ghb[(gs << 6) | lane];
#pragma unroll
      for (int off = 1; off < 64; off <<= 1) {
        int src = lane + off;
        int o = __shfl(fv, src < 64 ? src : 63);
        if (src < 64) fv += o;
      }
      int cum = beyond + fv;
      u64 pm2 = __ballot(cum >= TARGET);
      int tr = 63 - __builtin_clzll(pm2);
      T_A = (gs << 6) + tr;
      S_A = __shfl(cum, tr);
    } else {
      S_A = __shfl(v, 0);
    }
    if (lane == 0) { misc[0] = T_A; misc[2] = S_A; misc[4] = 0; }
  }
  __syncthreads();
  int T_A = misc[0], S_A = misc[2];
  bool modeB = (S_A > CAPA);
  int K = 0, nkept = 0;

  if (!modeB) {
    // Ballot-aggregated compaction of buckets >= T_A into U.
    for (int s = 0; s < SEG; s++) {
      const u64* gseg = gk + (size_t)s * SEGCAP;
      int Mg = Mseg[s];
      for (int t0 = 0; t0 < Mg; t0 += 1024) {
        int t = t0 + tid;
        bool pred = false;
        u64 key = 0;
        if (t < Mg) {
          key = __hip_atomic_load(&gseg[t], __ATOMIC_RELAXED,
                                  __HIP_MEMORY_SCOPE_AGENT);
          int bi = (int)(key >> KSHIFT) - HBASE;
          bi = min(max(bi, 0), NB - 1);
          pred = (bi >= T_A);
        }
        u64 mk = __ballot(pred);
        if (mk) {
          int wbase = 0;
          if (lane == 0) wbase = atomicAdd(&misc[4], __popcll(mk));
          wbase = __shfl(wbase, 0);
          if (pred) {
            int pos = wbase + __popcll(mk & ((1ull << lane) - 1));
            if (pos < CAPA) U[pos] = key;
          }
        }
      }
    }
    __syncthreads();
    int S = misc[4];
    if (S > CAPA) S = CAPA;
    // Rank-scatter sort (distinct keys -> perfect permutation).
    if (tid == 0 && (S & 1)) U[S] = 0ULL;
    __syncthreads();
    if (tid < S) {
      u64 k1 = U[tid];
      int r1 = 0;
      const ulonglong2* U2 = (const ulonglong2*)U;
      int half = (S + 1) >> 1;
      for (int k = 0; k < half; k++) {
        ulonglong2 kk = U2[k];  // uniform addr -> LDS broadcast
        r1 += (kk.x > k1) + (kk.y > k1);
      }
      SS[r1] = k1;
    }
    __syncthreads();
    K = S;
    for (int j = tid; j < K; j += 1024)
      bxA[j] = decode_one(SS[j], reg, props, b, h, w, offscale);
    __syncthreads();

    // Suppression bit-matrix: rb[i][w] bit jj set iff j=64w+jj>i and IoU>0.5.
    int nwords = (S + 63) >> 6;
    int ntiles = nwords * (nwords + 1) / 2;
    for (int t = wid; t < ntiles; t += 16) {
      int ti = 0, rem = t;
      while (rem >= nwords - ti) { rem -= nwords - ti; ti++; }
      int tj = ti + rem;
      int i = (ti << 6) + lane;
      float4 bi4 = bxA[i];  // i<512 allocated; garbage ok if i>=S (no write)
      float ai = (bi4.z - bi4.x) * (bi4.w - bi4.y);
      u64 bits = 0;
      int jbase = tj << 6;
      int jcount = min(64, S - jbase);
      for (int jj = 0; jj < jcount; jj++) {
        int j = jbase + jj;
        float4 bj = bxA[j];  // uniform addr -> broadcast
        float aj = (bj.z - bj.x) * (bj.w - bj.y);
        float iw = fmaxf(fminf(bi4.z, bj.z) - fmaxf(bi4.x, bj.x), 0.0f);
        float ih = fmaxf(fminf(bi4.w, bj.w) - fmaxf(bi4.y, bj.y), 0.0f);
        float inter = iw * ih;
        float iou = inter / (ai + aj - inter + 1e-6f);
        if (j > i && iou > 0.5f) bits |= (1ull << jj);
      }
      if (i < S) rb[i * 8 + tj] = bits;
    }
    __syncthreads();

    // Greedy bit-scan (wave 0): next-i via DPP min (VALU-only cross-lane).
    if (tid < 64) {
      u64 alive = 0;
      if (lane < nwords) {
        alive = ~0ull;
        int remb = S & 63;
        if (lane == nwords - 1 && remb) alive = (1ull << remb) - 1;
      }
      int nk = 0;
      if (S > 0) {
        int i = 0;
        for (;;) {
          if (lane == 0) outl[nk] = i;
          nk++;
          if (nk >= MAXDET) break;
          if (lane == (i >> 6)) alive &= ~(1ull << (i & 63));
          u64 row = (lane < nwords) ? rb[i * 8 + lane] : 0ull;
          u64 a2 = alive & ~row;  // rows w < i>>6 unwritten: alive=0 there
          alive = a2;
          int cnd = a2 ? ((lane << 6) + (int)__builtin_ctzll(a2)) : BIGI;
          int m8 = dpp_min8(cnd);
          i = __builtin_amdgcn_readfirstlane(m8);
          if (i >= BIGI) break;
        }
      }
      if (lane == 0) misc[6] = nk;
    }
    __syncthreads();
    nkept = misc[6];
    if (nkept < MAXDET && K < M && K < KPRE) modeB = true;
  }

  if (modeB) {  // never taken in practice; exact fallback (R5's proven path)
    __syncthreads();
    u32* hA = (u32*)(bp + 0);
    u32* hB = (u32*)(bp + 9248);
    for (int i = tid; i < NB; i += 1024) hA[i] = 0;
    if (tid == 0) { misc[1] = 0; misc[4] = 0; }
    __syncthreads();
    for (int s = 0; s < SEG; s++) {
      const u64* gseg = gk + (size_t)s * SEGCAP;
      for (int t = tid; t < Mseg[s]; t += 1024) {
        int bi = (int)(gseg[t] >> KSHIFT) - HBASE;
        bi = min(max(bi, 0), NB - 1);
        atomicAdd(&hA[bi], 1u);
      }
    }
    __syncthreads();
    u32 *src = hA, *dst = hB;
    for (int d = 1; d < NB; d <<= 1) {
      for (int i = tid; i < NB; i += 1024) {
        u32 v = src[i];
        if (i + d < NB) v += src[i + d];
        dst[i] = v;
      }
      __syncthreads();
      u32* tmp = src; src = dst; dst = tmp;
    }
    for (int i = tid; i < NB; i += 1024)
      if (src[i] >= (u32)KPRE) atomicMax(&misc[1], i);
    __syncthreads();
    if (tid == 0) {
      int TB = misc[1];
      int SB = (int)src[TB];
      if (SB > CAPB && TB + 1 < NB) misc[1] = TB + 1;  // fat-bucket guard
    }
    __syncthreads();
    int TB = misc[1];
    for (int s = 0; s < SEG; s++) {
      const u64* gseg = gk + (size_t)s * SEGCAP;
      for (int t = tid; t < Mseg[s]; t += 1024) {
        u64 key = gseg[t];
        int bi = (int)(key >> KSHIFT) - HBASE;
        bi = min(max(bi, 0), NB - 1);
        if (bi >= TB) { int p = atomicAdd(&misc[4], 1); if (p < CAPB) U[p] = key; }
      }
    }
    __syncthreads();
    int S = misc[4]; if (S > CAPB) S = CAPB;
    {
      int j1 = tid, j2 = tid + 1024;
      u64 k1 = (j1 < S) ? U[j1] : 0ULL;
      u64 k2 = (j2 < S) ? U[j2] : 0ULL;
      int r1 = 0, r2 = 0;
      for (int k = 0; k < S; k++) { u64 kk = U[k]; r1 += (kk > k1); r2 += (kk > k2); }
      __syncthreads();
      if (j1 < S) SS[r1] = k1;
      if (j2 < S) SS[r2] = k2;
    }
    __syncthreads();
    K = (S < KPRE) ? S : KPRE;
    for (int j = tid; j < K; j += 1024) {
      bxB[j] = decode_one(SS[j], reg, props, b, h, w, offscale);
      keepB[j] = 1;
    }
    __syncthreads();
    int nk = 0;
    if (K > 0) {
      int i = 0;
      for (;;) {
        if (tid == 0) { outl[nk] = i; misc[5] = K; }
        nk++;
        if (nk >= MAXDET) break;
        __syncthreads();
        float4 tb = bxB[i];
        float ai = (tb.z - tb.x) * (tb.w - tb.y);
        int ln = K;
        for (int jj = i + 1 + tid; jj < K; jj += 1024) {
          if (!keepB[jj]) continue;
          float4 bj = bxB[jj];
          float aj = (bj.z - bj.x) * (bj.w - bj.y);
          float iw = fmaxf(fminf(tb.z, bj.z) - fmaxf(tb.x, bj.x), 0.0f);
          float ih = fmaxf(fminf(tb.w, bj.w) - fmaxf(tb.y, bj.y), 0.0f);
          float inter = iw * ih;
          float iou = inter / (ai + aj - inter + 1e-6f);
          if (iou > 0.5f) keepB[jj] = 0;
          else ln = min(ln, jj);
        }
#pragma unroll
        for (int off = 32; off; off >>= 1) ln = min(ln, __shfl_xor(ln, off));
        if ((tid & 63) == 0 && ln < K) atomicMin(&misc[5], ln);
        __syncthreads();
        int ni = misc[5];
        __syncthreads();
        if (ni >= K) break;
        i = ni;
      }
    }
    if (tid == 0) misc[6] = nk;
    __syncthreads();
    nkept = misc[6];
  }

  // Output: boxes [B,100,4] | scores [B,100] | labels [B,100] (as float).
  float4* bx = modeB ? bxB : bxA;
  float* oBox = out;
  float* oSc = out + B_ * MAXDET * 4;
  float* oLb = out + B_ * MAXDET * 5;
  for (int k2 = tid; k2 < MAXDET; k2 += 1024) {
    float4 bb = make_float4(0.0f, 0.0f, 0.0f, 0.0f);
    float sv = 0.0f, lv = -1.0f;
    if (k2 < nkept) {
      int idx = outl[k2];
      u64 kk = SS[idx];
      sv = __uint_as_float((u32)(kk >> 32));
      unsigned fi = 0xFFFFFFFFu - (u32)kk;
      int c = (int)(fi % (unsigned)C_);
      float off = (float)c * offscale;
      float4 ob = bx[idx];
      bb = make_float4(ob.x - off, ob.y - off, ob.z - off, ob.w - off);
      lv = (float)c;
    }
    oBox[(b * MAXDET + k2) * 4 + 0] = bb.x;
    oBox[(b * MAXDET + k2) * 4 + 1] = bb.y;
    oBox[(b * MAXDET + k2) * 4 + 2] = bb.z;
    oBox[(b * MAXDET + k2) * 4 + 3] = bb.w;
    oSc[b * MAXDET + k2] = sv;
    oLb[b * MAXDET + k2] = lv;
  }
}

extern "C" void kernel_launch(void* const* d_in, const int* in_sizes, int n_in,
                              void* d_out, int out_size, void* d_ws, size_t ws_size,
                              hipStream_t stream) {
  const float* cls = (const float*)d_in[0];    // [B,N,81] f32
  const float* reg = (const float*)d_in[1];    // [B,N,320] f32
  const float* props = (const float*)d_in[2];  // [B,N,4] f32
  const int* hw = (const int*)d_in[3];         // [B,2] i32
  float* out = (float*)d_out;                  // 2400 f32

  int* gcnt = (int*)d_ws;                              // [0,64)
  u32* done = (u32*)((char*)d_ws + 64);                // [64,68)
  u32* ghist = (u32*)((char*)d_ws + 128);              // [128,38016)
  u64* gkeys = (u64*)((char*)d_ws + 38016);            // 256 KiB

  hipMemsetAsync(d_ws, 0, 38016, stream);  // zero counters + done + histograms

  fused_kernel<<<NPROD + NCONS, 1024, 0, stream>>>(
      cls, reg, props, hw, gcnt, done, ghist, gkeys, out);
}